// Round 12
// baseline (856.598 us; speedup 1.0000x reference)
//
#include <hip/hip_runtime.h>

#define SEQ   512
#define NTHR  1024
#define NBLK  256

typedef _Float16 f16x8 __attribute__((ext_vector_type(8)));
typedef float    f32x4 __attribute__((ext_vector_type(4)));

#define MFMA(a, b, c) __builtin_amdgcn_mfma_f32_16x16x32_f16((a), (b), (c), 0, 0, 0)

__device__ __forceinline__ float sig_(float x) {
    return __builtin_amdgcn_rcpf(1.0f + __builtin_amdgcn_exp2f(x * -1.4426950408889634f));
}
__device__ __forceinline__ float tanh_(float x) {
    return fmaf(2.0f, __builtin_amdgcn_rcpf(1.0f + __builtin_amdgcn_exp2f(x * -2.8853900817779268f)), -1.0f);
}

// one pipeline tick for this wave. RD/WR are byte offsets of the read/write
// parity slots (compile-time literals in the unrolled main loop).
#define TICK(RD, WR, TAU, CHECKED)                                             \
    {                                                                          \
        const int t = (TAU) - ell;                                             \
        if (!(CHECKED) || ((unsigned)t < (unsigned)SEQ)) {                     \
            f16x8 b0, b1, b2, b3;                                              \
            if (ell == 0) {                                                    \
                b0 = *(const f16x8*)(hb + aSelf0 + (RD));                      \
                b1 = *(const f16x8*)(hb + aSelf1 + (RD));                      \
                f16x8 xf;                                                      \
                _Pragma("unroll")                                              \
                for (int e = 0; e < 8; ++e) xf[e] = (_Float16)0.0f;            \
                if (lam == 0) xf[0] = (_Float16)xrow[t];                       \
                b2 = xf; b3 = xf;                                              \
            } else {                                                           \
                b0 = *(const f16x8*)(hb + aIn0 + (RD));                        \
                b1 = *(const f16x8*)(hb + aIn1 + (RD));                        \
                b2 = *(const f16x8*)(hb + aSelf0 + (RD));                      \
                b3 = *(const f16x8*)(hb + aSelf1 + (RD));                      \
            }                                                                  \
            __builtin_amdgcn_s_setprio(1);                                     \
            f32x4 A0 = MFMA(wf[0][0], b0, biasv[0]);                           \
            f32x4 A1 = MFMA(wf[1][0], b0, biasv[1]);                           \
            f32x4 A2 = MFMA(wf[2][0], b0, biasv[2]);                           \
            f32x4 A3 = MFMA(wf[3][0], b0, biasv[3]);                           \
            A0 = MFMA(wf[0][1], b1, A0);  A1 = MFMA(wf[1][1], b1, A1);         \
            A2 = MFMA(wf[2][1], b1, A2);  A3 = MFMA(wf[3][1], b1, A3);         \
            A0 = MFMA(wf[0][2], b2, A0);  A1 = MFMA(wf[1][2], b2, A1);         \
            A2 = MFMA(wf[2][2], b2, A2);  A3 = MFMA(wf[3][2], b2, A3);         \
            if (ell != 0) {                                                    \
                A0 = MFMA(wf[0][3], b3, A0);  A1 = MFMA(wf[1][3], b3, A1);     \
                A2 = MFMA(wf[2][3], b3, A2);  A3 = MFMA(wf[3][3], b3, A3);     \
            }                                                                  \
            __builtin_amdgcn_s_setprio(0);                                     \
            const f32x4 s01 = k1b ? A1 : A0;                                   \
            const f32x4 s23 = k1b ? A3 : A2;                                   \
            const f32x4 aK  = k2b ? s23 : s01;                                 \
            const float gi = sig_(aK[0]);                                      \
            const float gf = sig_(aK[1]);                                      \
            const float gg = tanh_(aK[2]);                                     \
            const float go = sig_(aK[3]);                                      \
            cstK = fmaf(gf, cstK, gi * gg);                                    \
            const float hn = go * tanh_(cstK);                                 \
            *(_Float16*)(hb + wrKS + (WR)) = (_Float16)hn;                     \
            if (ell == 3) {                                                    \
                float v1 = hn, v2 = hn * hn, v3 = hn * gwK;                    \
                v1 += __shfl_xor(v1, 4, 64);  v2 += __shfl_xor(v2, 4, 64);  v3 += __shfl_xor(v3, 4, 64);  \
                v1 += __shfl_xor(v1, 8, 64);  v2 += __shfl_xor(v2, 8, 64);  v3 += __shfl_xor(v3, 8, 64);  \
                v1 += __shfl_xor(v1, 16, 64); v2 += __shfl_xor(v2, 16, 64); v3 += __shfl_xor(v3, 16, 64); \
                v1 += __shfl_xor(v1, 32, 64); v2 += __shfl_xor(v2, 32, 64); v3 += __shfl_xor(v3, 32, 64); \
                if (bc < 4) {                                                  \
                    float* pp = &part[t & 15][om][bc][0];                      \
                    pp[0] = v1; pp[1] = v2; pp[2] = v3;                        \
                }                                                              \
            }                                                                  \
        }                                                                      \
        __syncthreads();                                                       \
    }

// LN + projection for the 8 timesteps ending at T3 (runs after a barrier)
#define COMBINE(T3)                                                            \
    {                                                                          \
        const int row = tid >> 4, sub = tid & 15;                              \
        if (row < 32) {                                                        \
            const int sl = row >> 2, b = row & 3;                              \
            const int slot = ((T3) - 7 + sl) & 15;                             \
            float u1 = part[slot][sub & 3][b][0];                              \
            float u2 = part[slot][sub & 3][b][1];                              \
            float u3 = part[slot][sub & 3][b][2];                              \
            u1 += __shfl_xor(u1, 1, 64); u2 += __shfl_xor(u2, 1, 64); u3 += __shfl_xor(u3, 1, 64); \
            u1 += __shfl_xor(u1, 2, 64); u2 += __shfl_xor(u2, 2, 64); u3 += __shfl_xor(u3, 2, 64); \
            if (sub == 0) {                                                    \
                const float mu = u1 * (1.0f / 64.0f);                          \
                float var = fmaf(u2, 1.0f / 64.0f, -mu * mu);                  \
                var = fmaxf(var, 0.0f);                                        \
                const float rs = rsqrtf(var + 1e-5f);                         \
                out[(bb * 4 + b) * SEQ + ((T3) - 7) + sl] = fmaf(rs, fmaf(-mu, Sgw, u3), Sbw); \
            }                                                                  \
        }                                                                      \
    }

__global__ __launch_bounds__(NTHR, 4) void lstm4_pipe16c(
    const float* __restrict__ x,
    const float* __restrict__ W0, const float* __restrict__ B0,
    const float* __restrict__ W1, const float* __restrict__ B1,
    const float* __restrict__ W2, const float* __restrict__ B2,
    const float* __restrict__ W3, const float* __restrict__ B3,
    const float* __restrict__ ln_g, const float* __restrict__ ln_b,
    const float* __restrict__ Wout, const float* __restrict__ bout,
    float* __restrict__ out)
{
    __shared__ __align__(16) _Float16 hbuf[2][4][4][64];   // [parity][layer][b][k] 4 KB
    __shared__ float xall[4][SEQ];                         // 8 KB
    __shared__ float part[16][4][4][3];                    // 3 KB
    __shared__ float sconst[2];

    const int tid  = threadIdx.x;
    const int lane = tid & 63;
    const int w    = tid >> 6;
    const int ell  = w >> 2;
    const int om   = w & 3;
    const int lam  = lane >> 4;
    const int bc   = lane & 15;
    const int br   = bc & 3;
    const int kq   = bc >> 2;
    const int bb   = blockIdx.x;

    for (int i = tid; i < 4 * SEQ; i += NTHR)
        xall[i >> 9][i & 511] = x[bb * 4 * SEQ + i];
    for (int i = tid; i < 2 * 4 * 4 * 64; i += NTHR)
        ((_Float16*)hbuf)[i] = (_Float16)0.0f;

    if (tid < 64) {
        float a = ln_g[tid] * Wout[tid];
        float b = ln_b[tid] * Wout[tid];
#pragma unroll
        for (int off = 32; off > 0; off >>= 1) {
            a += __shfl_xor(a, off, 64);
            b += __shfl_xor(b, off, 64);
        }
        if (tid == 0) { sconst[0] = a; sconst[1] = b; }
    }

    const float* Wp = (ell == 0) ? W0 : (ell == 1) ? W1 : (ell == 2) ? W2 : W3;
    const float* Bp = (ell == 0) ? B0 : (ell == 1) ? B1 : (ell == 2) ? B2 : B3;

    f16x8 wf[4][4];
    f32x4 biasv[4];
#pragma unroll
    for (int i = 0; i < 4; ++i) {
        const int T  = om * 4 + i;
        const int cA = (bc & 3) * 64 + T * 4 + (bc >> 2);
        if (ell == 0) {
#pragma unroll
            for (int kt = 0; kt < 2; ++kt)
#pragma unroll
                for (int e = 0; e < 8; ++e)
                    wf[i][kt][e] = (_Float16)W0[(1 + kt * 32 + lam * 8 + e) * 256 + cA];
#pragma unroll
            for (int e = 0; e < 8; ++e) { wf[i][2][e] = (_Float16)0.0f; wf[i][3][e] = (_Float16)0.0f; }
            if (lam == 0) wf[i][2][0] = (_Float16)W0[cA];
        } else {
#pragma unroll
            for (int kt = 0; kt < 4; ++kt)
#pragma unroll
                for (int e = 0; e < 8; ++e)
                    wf[i][kt][e] = (_Float16)Wp[(kt * 32 + lam * 8 + e) * 256 + cA];
        }
#pragma unroll
        for (int r = 0; r < 4; ++r)
            biasv[i][r] = Bp[r * 64 + T * 4 + lam];
    }

    const int   mK  = (om * 4 + kq) * 4 + lam;
    const float gwK = ln_g[mK] * Wout[mK];
    const int   wrK = br * 128 + (((mK >> 3) ^ br) * 16) + (mK & 7) * 2;

    const int a0 = br * 128 + ((lam)     ^ br) * 16;
    const int a1 = br * 128 + ((4 + lam) ^ br) * 16;

    // precomputed per-wave LDS address bases (parity offset added as literal)
    const int offIn   = (ell == 0) ? 0 : (ell - 1) * 512;
    const int offSelf = ell * 512;
    const int aIn0 = a0 + offIn,   aIn1 = a1 + offIn;
    const int aSelf0 = a0 + offSelf, aSelf1 = a1 + offSelf;
    const int wrKS = wrK + offSelf;
    const float* const xrow = &xall[br][0];

    const bool k1b = (bc & 4) != 0;
    const bool k2b = (bc & 8) != 0;

    float cstK = 0.0f;
    char* const hb = (char*)hbuf;

    __syncthreads();
    const float Sgw = sconst[0];
    const float Sbw = sconst[1] + bout[0];

    // ---- prologue: tau = 0..3 (checked, runtime parity) ----
    for (int tau = 0; tau < 4; ++tau) {
        const int RDp = ((tau + 1) & 1) * 2048;
        const int WRp = (tau & 1) * 2048;
        TICK(RDp, WRp, tau, true)
        const int t3 = tau - 3;
        if (t3 >= 7 && (t3 & 7) == 7) COMBINE(t3)
    }

    // ---- main: tau = 4..511, x4 unrolled, branchless, compile-time parity ----
    for (int j = 0; j < 127; ++j) {
        const int tbase = 4 + 4 * j;
        TICK(2048, 0, tbase + 0, false)
        TICK(0, 2048, tbase + 1, false)
        TICK(2048, 0, tbase + 2, false)
        if ((tbase & 7) == 0) COMBINE(tbase - 1)       // t3 = tbase-1, every other iter
        TICK(0, 2048, tbase + 3, false)
    }

    // ---- epilogue: tau = 512..514 (checked) ----
    for (int tau = SEQ; tau < SEQ + 3; ++tau) {
        const int RDp = ((tau + 1) & 1) * 2048;
        const int WRp = (tau & 1) * 2048;
        TICK(RDp, WRp, tau, true)
        const int t3 = tau - 3;
        if (t3 >= 7 && (t3 & 7) == 7) COMBINE(t3)
    }
}

extern "C" void kernel_launch(void* const* d_in, const int* in_sizes, int n_in,
                              void* d_out, int out_size, void* d_ws, size_t ws_size,
                              hipStream_t stream)
{
    const float* x    = (const float*)d_in[0];
    const float* W0   = (const float*)d_in[1];
    const float* B0   = (const float*)d_in[2];
    const float* W1   = (const float*)d_in[3];
    const float* B1   = (const float*)d_in[4];
    const float* W2   = (const float*)d_in[5];
    const float* B2   = (const float*)d_in[6];
    const float* W3   = (const float*)d_in[7];
    const float* B3   = (const float*)d_in[8];
    const float* ln_g = (const float*)d_in[9];
    const float* ln_b = (const float*)d_in[10];
    const float* Wout = (const float*)d_in[11];
    const float* bout = (const float*)d_in[12];
    float* out = (float*)d_out;

    lstm4_pipe16c<<<NBLK, NTHR, 0, stream>>>(x, W0, B0, W1, B1, W2, B2, W3, B3,
                                             ln_g, ln_b, Wout, bout, out);
}

// Round 13
// 559.836 us; speedup vs baseline: 1.5301x; 1.5301x over previous
//
#include <hip/hip_runtime.h>

#define SEQ   512
#define NTHR  1024
#define NBLK  256

typedef _Float16 f16x8 __attribute__((ext_vector_type(8)));
typedef float    f32x4 __attribute__((ext_vector_type(4)));

#define MFMA(a, b, c) __builtin_amdgcn_mfma_f32_16x16x32_f16((a), (b), (c), 0, 0, 0)

__device__ __forceinline__ float sig_(float x) {
    return __builtin_amdgcn_rcpf(1.0f + __builtin_amdgcn_exp2f(x * -1.4426950408889634f));
}
// sign-safe tanh via 2*sigmoid(2x)-1
__device__ __forceinline__ float tanh_(float x) {
    return fmaf(2.0f, __builtin_amdgcn_rcpf(1.0f + __builtin_amdgcn_exp2f(x * -2.8853900817779268f)), -1.0f);
}

// Layer-pipelined, 16 waves: wave w -> layer ell=w>>2, quarter om=w&3 (4 M-tiles).
// Tick tau: layer ell processes t = tau - ell. ONE barrier per tick.
// Gate-post: replica-quad member k=bc>>2 owns tile k fully IN-LANE.
// NEW (round 13): static per-wave priority ladder. Wave->SIMD assignment is
// w&3, so SIMD s hosts waves {s, s+4, s+8, s+12} = one wave per LAYER (ell =
// w>>2 distinct). Setting prio=ell makes the matrix pipe serve resident waves
// in a fixed order, so the first-served wave's gate VALU overlaps the others'
// MFMA streams instead of all waves phase-locking (MFMA burst, then VALU burst).
__global__ __launch_bounds__(NTHR, 4) void lstm4_pipe16d(
    const float* __restrict__ x,
    const float* __restrict__ W0, const float* __restrict__ B0,
    const float* __restrict__ W1, const float* __restrict__ B1,
    const float* __restrict__ W2, const float* __restrict__ B2,
    const float* __restrict__ W3, const float* __restrict__ B3,
    const float* __restrict__ ln_g, const float* __restrict__ ln_b,
    const float* __restrict__ Wout, const float* __restrict__ bout,
    float* __restrict__ out)
{
    __shared__ __align__(16) _Float16 hbuf[2][4][4][64];   // 4 KB  [parity][layer][b][k]
    __shared__ float xall[4][SEQ];                         // 8 KB
    __shared__ float part[16][4][4][3];                    // 3 KB LN partials [slot][om][b][c]
    __shared__ float sconst[2];

    const int tid  = threadIdx.x;
    const int lane = tid & 63;
    const int w    = tid >> 6;        // wave 0..15
    const int ell  = w >> 2;          // layer
    const int om   = w & 3;           // tile quarter
    const int lam  = lane >> 4;
    const int bc   = lane & 15;
    const int br   = bc & 3;
    const int k    = bc >> 2;         // quad member -> owned tile
    const int bb   = blockIdx.x;

    // ---- stage x, zero h (both parities) ----
    for (int i = tid; i < 4 * SEQ; i += NTHR)
        xall[i >> 9][i & 511] = x[bb * 4 * SEQ + i];
    for (int i = tid; i < 2 * 4 * 4 * 64; i += NTHR)
        ((_Float16*)hbuf)[i] = (_Float16)0.0f;

    if (tid < 64) {
        float a = ln_g[tid] * Wout[tid];
        float b = ln_b[tid] * Wout[tid];
#pragma unroll
        for (int off = 32; off > 0; off >>= 1) {
            a += __shfl_xor(a, off, 64);
            b += __shfl_xor(b, off, 64);
        }
        if (tid == 0) { sconst[0] = a; sconst[1] = b; }
    }

    const float* Wp = (ell == 0) ? W0 : (ell == 1) ? W1 : (ell == 2) ? W2 : W3;
    const float* Bp = (ell == 0) ? B0 : (ell == 1) ? B1 : (ell == 2) ? B2 : B3;

    // ---- per-wave weights: 4 tiles, gate-permuted cols; biases in VGPR ----
    f16x8 wf[4][4];
    f32x4 biasv[4];
#pragma unroll
    for (int i = 0; i < 4; ++i) {
        const int T  = om * 4 + i;
        const int cA = (bc & 3) * 64 + T * 4 + (bc >> 2);
        if (ell == 0) {
#pragma unroll
            for (int kt = 0; kt < 2; ++kt)
#pragma unroll
                for (int e = 0; e < 8; ++e)
                    wf[i][kt][e] = (_Float16)W0[(1 + kt * 32 + lam * 8 + e) * 256 + cA];
#pragma unroll
            for (int e = 0; e < 8; ++e) { wf[i][2][e] = (_Float16)0.0f; wf[i][3][e] = (_Float16)0.0f; }
            if (lam == 0) wf[i][2][0] = (_Float16)W0[cA];   // x weight, one-hot A-frag
        } else {
#pragma unroll
            for (int kt = 0; kt < 4; ++kt)        // kt 0..1 = in-h, 2..3 = self-h
#pragma unroll
                for (int e = 0; e < 8; ++e)
                    wf[i][kt][e] = (_Float16)Wp[(kt * 32 + lam * 8 + e) * 256 + cA];
        }
#pragma unroll
        for (int r = 0; r < 4; ++r)
            biasv[i][r] = Bp[r * 64 + T * 4 + lam];
    }

    // owned-tile constants
    const int   mK  = (om * 4 + k) * 4 + lam;
    const float gwK = ln_g[mK] * Wout[mK];
    const int   wrK = br * 128 + (((mK >> 3) ^ br) * 16) + (mK & 7) * 2;

    // LDS B-frag read offsets (16B-chunk XOR swizzle), pad lanes broadcast br
    const int a0 = br * 128 + ((lam)     ^ br) * 16;
    const int a1 = br * 128 + ((4 + lam) ^ br) * 16;

    const bool k1b = (bc & 4) != 0;
    const bool k2b = (bc & 8) != 0;

    float cstK = 0.0f;
    char* const hb = (char*)hbuf;

    __syncthreads();
    const float Sgw = sconst[0];
    const float Sbw = sconst[1] + bout[0];

    // ---- static priority ladder: one wave per layer per SIMD, distinct prio ----
    if      (ell == 3) __builtin_amdgcn_s_setprio(3);
    else if (ell == 2) __builtin_amdgcn_s_setprio(2);
    else if (ell == 1) __builtin_amdgcn_s_setprio(1);
    // ell == 0 stays at default prio 0

    for (int tau = 0; tau < SEQ + 3; ++tau) {
        const char* bR = hb + (((tau + 1) & 1) ? 2048 : 0);   // written last tick
        char*       bW = hb + (((tau    ) & 1) ? 2048 : 0);   // written this tick
        const int  t      = tau - ell;
        const bool active = (t >= 0) && (t < SEQ);

        if (active) {
            f16x8 b0, b1, b2, b3;
            if (ell == 0) {
                b0 = *(const f16x8*)(bR + a0);         // self-h (layer 0 buffer)
                b1 = *(const f16x8*)(bR + a1);
                f16x8 xf;
#pragma unroll
                for (int e = 0; e < 8; ++e) xf[e] = (_Float16)0.0f;
                if (lam == 0) xf[0] = (_Float16)xall[br][t];   // one-hot x B-frag
                b2 = xf; b3 = xf;
            } else {
                const char* bIn   = bR + (ell - 1) * 512;
                const char* bSelf = bR + ell * 512;
                b0 = *(const f16x8*)(bIn + a0);
                b1 = *(const f16x8*)(bIn + a1);
                b2 = *(const f16x8*)(bSelf + a0);
                b3 = *(const f16x8*)(bSelf + a1);
            }

            f32x4 A0 = MFMA(wf[0][0], b0, biasv[0]);
            f32x4 A1 = MFMA(wf[1][0], b0, biasv[1]);
            f32x4 A2 = MFMA(wf[2][0], b0, biasv[2]);
            f32x4 A3 = MFMA(wf[3][0], b0, biasv[3]);
            A0 = MFMA(wf[0][1], b1, A0);  A1 = MFMA(wf[1][1], b1, A1);
            A2 = MFMA(wf[2][1], b1, A2);  A3 = MFMA(wf[3][1], b1, A3);
            A0 = MFMA(wf[0][2], b2, A0);  A1 = MFMA(wf[1][2], b2, A1);
            A2 = MFMA(wf[2][2], b2, A2);  A3 = MFMA(wf[3][2], b2, A3);
            A0 = MFMA(wf[0][3], b3, A0);  A1 = MFMA(wf[1][3], b3, A1);
            A2 = MFMA(wf[2][3], b3, A2);  A3 = MFMA(wf[3][3], b3, A3);

            // select owned tile k's acc (cndmask ladder, no array indexing)
            const f32x4 s01 = k1b ? A1 : A0;
            const f32x4 s23 = k1b ? A3 : A2;
            const f32x4 aK  = k2b ? s23 : s01;

            // straight-line in-lane gates
            const float gi = sig_(aK[0]);
            const float gf = sig_(aK[1]);
            const float gg = tanh_(aK[2]);
            const float go = sig_(aK[3]);
            cstK = fmaf(gf, cstK, gi * gg);
            const float hn = go * tanh_(cstK);
            *(_Float16*)(bW + ell * 512 + wrK) = (_Float16)hn;   // all 64 lanes, 1 write each

            if (ell == 3) {
                float v1 = hn, v2 = hn * hn, v3 = hn * gwK;
                v1 += __shfl_xor(v1, 4, 64);  v2 += __shfl_xor(v2, 4, 64);  v3 += __shfl_xor(v3, 4, 64);
                v1 += __shfl_xor(v1, 8, 64);  v2 += __shfl_xor(v2, 8, 64);  v3 += __shfl_xor(v3, 8, 64);
                v1 += __shfl_xor(v1, 16, 64); v2 += __shfl_xor(v2, 16, 64); v3 += __shfl_xor(v3, 16, 64);
                v1 += __shfl_xor(v1, 32, 64); v2 += __shfl_xor(v2, 32, 64); v3 += __shfl_xor(v3, 32, 64);
                if (bc < 4) {
                    float* pp = &part[t & 15][om][bc][0];
                    pp[0] = v1; pp[1] = v2; pp[2] = v3;
                }
            }
        }
        __syncthreads();

        // ---- LN + projection for 8 finished timesteps ----
        const int t3 = tau - 3;
        if (t3 >= 7 && (t3 & 7) == 7) {
            const int row = tid >> 4, sub = tid & 15;
            if (row < 32) {
                const int sl = row >> 2, b = row & 3;
                const int slot = (t3 - 7 + sl) & 15;
                float u1 = part[slot][sub & 3][b][0];
                float u2 = part[slot][sub & 3][b][1];
                float u3 = part[slot][sub & 3][b][2];
                u1 += __shfl_xor(u1, 1, 64); u2 += __shfl_xor(u2, 1, 64); u3 += __shfl_xor(u3, 1, 64);
                u1 += __shfl_xor(u1, 2, 64); u2 += __shfl_xor(u2, 2, 64); u3 += __shfl_xor(u3, 2, 64);
                if (sub == 0) {
                    const float mu = u1 * (1.0f / 64.0f);
                    float var = fmaf(u2, 1.0f / 64.0f, -mu * mu);
                    var = fmaxf(var, 0.0f);
                    const float rs = rsqrtf(var + 1e-5f);
                    out[(bb * 4 + b) * SEQ + (t3 - 7) + sl] = fmaf(rs, fmaf(-mu, Sgw, u3), Sbw);
                }
            }
        }
    }
}

extern "C" void kernel_launch(void* const* d_in, const int* in_sizes, int n_in,
                              void* d_out, int out_size, void* d_ws, size_t ws_size,
                              hipStream_t stream)
{
    const float* x    = (const float*)d_in[0];
    const float* W0   = (const float*)d_in[1];
    const float* B0   = (const float*)d_in[2];
    const float* W1   = (const float*)d_in[3];
    const float* B1   = (const float*)d_in[4];
    const float* W2   = (const float*)d_in[5];
    const float* B2   = (const float*)d_in[6];
    const float* W3   = (const float*)d_in[7];
    const float* B3   = (const float*)d_in[8];
    const float* ln_g = (const float*)d_in[9];
    const float* ln_b = (const float*)d_in[10];
    const float* Wout = (const float*)d_in[11];
    const float* bout = (const float*)d_in[12];
    float* out = (float*)d_out;

    lstm4_pipe16d<<<NBLK, NTHR, 0, stream>>>(x, W0, B0, W1, B1, W2, B2, W3, B3,
                                             ln_g, ln_b, Wout, bout, out);
}